// Round 5
// baseline (174.843 us; speedup 1.0000x reference)
//
#include <hip/hip_runtime.h>
#include <stdint.h>

// AttentionHead: out = softmax(QK^T/sqrt(dk) - 1e15*mask) @ V, Q/K/V = inputs @ W{q,k,v}
// B=4 S=2048 E=1024 D=128. bf16 MFMA; swapped-QK^T flash (exp2 domain), fused mask pack,
// A-read-once fused QKV projection.

#define SEQ   2048
#define EDIM  1024
#define DDIM  128
#define QS2   0.1275174329f   // (1/sqrt(128)) * log2(e)

typedef unsigned short u16;
typedef unsigned int   u32;
using short8 = __attribute__((ext_vector_type(8))) short;   // 8 x bf16 (4 VGPR) MFMA frag
using f32x4  = __attribute__((ext_vector_type(4))) float;
using int4v  = __attribute__((ext_vector_type(4))) int;
using u32x2  = __attribute__((ext_vector_type(2))) unsigned int;

__device__ __forceinline__ u16 f2bf(float x) {              // f32 -> bf16 RNE
    uint32_t u = __float_as_uint(x);
    return (u16)((u + 0x7fffu + ((u >> 16) & 1u)) >> 16);
}
__device__ __forceinline__ float ex2(float x) {             // 2^x
    float r; asm("v_exp_f32 %0, %1" : "=v"(r) : "v"(x)); return r;
}

// async global->LDS 16B per lane; LDS dst = wave-uniform base + lane*16 (linear).
__device__ __forceinline__ void gld16(const void* gsrc, void* lds_dst) {
    __builtin_amdgcn_global_load_lds(
        (const __attribute__((address_space(1))) uint32_t*)(uintptr_t)gsrc,
        (__attribute__((address_space(3))) uint32_t*)(uint32_t)(uintptr_t)lds_dst,
        16, 0, 0);
}

// ---------------- kernel 1: W f32 [1024][128]x3 -> Wt bf16 [384 n][1024 k] ---------------
__global__ __launch_bounds__(256) void prep_kernel(
    const float* __restrict__ Wq, const float* __restrict__ Wk, const float* __restrict__ Wv,
    u16* __restrict__ Wt)
{
    __shared__ u16 tl[64][65];
    const int t = blockIdx.x;            // 96 = 3 mats * 32 tiles (16 k-tiles x 2 n-tiles)
    const int tid = threadIdx.x;
    const int wsel = t >> 5;
    const int tile = t & 31;
    const int k0 = (tile >> 1) * 64;
    const int n0 = (tile & 1) * 64;
    const float* W = (wsel == 0) ? Wq : ((wsel == 1) ? Wk : Wv);
#pragma unroll
    for (int it = 0; it < 16; ++it) {
        const int idx = it * 256 + tid;
        const int r = idx >> 6, c = idx & 63;
        tl[c][r] = f2bf(W[(size_t)(k0 + r) * DDIM + n0 + c]);
    }
    __syncthreads();
    u16* Wtp = Wt + (size_t)wsel * DDIM * EDIM;
#pragma unroll
    for (int it = 0; it < 16; ++it) {
        const int idx = it * 256 + tid;
        const int r = idx >> 6, c = idx & 63;
        Wtp[(size_t)(n0 + r) * EDIM + k0 + c] = tl[r][c];
    }
}

// ---------------- kernel 2: fused QKV projection -----------------------------------------
// 256 blocks (XCD-swizzled) x 512 thr (8 waves). Tile 32m x 384n (Q|K|V), BK=64,
// double-buffered staging. Wave w owns nfrags {w, w+8, w+16} -> Q col, K col, V col.
// Outputs: Q bf16 [8192][128] (pre-scaled by QS2), K bf16, Vt bf16 [B][128][S].
__global__ __launch_bounds__(512, 1) void proj_kernel(
    const float* __restrict__ Ain, const u16* __restrict__ Wtb,
    u16* __restrict__ Qb, u16* __restrict__ Kb, u16* __restrict__ Vtb)
{
    __shared__ __align__(16) uint8_t smem[106496];  // A[2] 8KB @0, Wt[2] 96KB @8192
    const int tid = threadIdx.x;
    const int w = tid >> 6, lane = tid & 63;
    const int lq = lane & 15, lg = lane >> 4;

    const int bid = blockIdx.x;                      // 256 = 8 xcd * 32
    const int wg = (bid & 7) * 32 + (bid >> 3);
    const int m0 = wg * 32;

    f32x4 acc[2][3] = {};

    auto stageP = [&](int buf, int kt) {
        const int k0 = kt * 64;
        uint8_t* wtb = smem + 8192 + buf * 49152;
        // Wt tile [384 n][64 k] via gld16, linear dest + inverse-swizzled source
#pragma unroll
        for (int i = 0; i < 6; ++i) {
            const int G = i * 512 + tid;
            const int n = G >> 3, c = G & 7;
            gld16(Wtb + (size_t)n * EDIM + k0 + ((c ^ (n & 7)) << 3),
                  wtb + i * 8192 + w * 1024);
        }
        // A tile [32 m][64 k] f32 -> bf16 reg-staged, swizzled ds_write_b64
        const int row = tid >> 4, c4 = tid & 15;
        const int c2 = c4 >> 1, h = c4 & 1;
        const float* s2 = Ain + (size_t)(m0 + row) * EDIM + k0 + c2 * 8 + h * 4;
        const f32x4 a0 = *(const f32x4*)s2;
        u32x2 pk;
        pk[0] = (u32)f2bf(a0[0]) | ((u32)f2bf(a0[1]) << 16);
        pk[1] = (u32)f2bf(a0[2]) | ((u32)f2bf(a0[3]) << 16);
        *(u32x2*)(smem + buf * 4096 + row * 128 + ((c2 ^ (row & 7)) << 4) + h * 8) = pk;
    };

    stageP(0, 0);
    __syncthreads();

#pragma unroll 1
    for (int kt = 0; kt < 16; ++kt) {
        const int cur = kt & 1;
        if (kt < 15) stageP(cur ^ 1, kt + 1);
        const uint8_t* abase = smem + cur * 4096;
        const uint8_t* wbase = smem + 8192 + cur * 49152;
        __builtin_amdgcn_s_setprio(1);
#pragma unroll
        for (int ks = 0; ks < 2; ++ks) {
            short8 af[2];
#pragma unroll
            for (int mf = 0; mf < 2; ++mf) {
                const int arow = mf * 16 + lq;
                af[mf] = *(const short8*)(abase + arow * 128 + ((((ks << 2) + lg) ^ (arow & 7)) << 4));
            }
#pragma unroll
            for (int j = 0; j < 3; ++j) {
                const int brow = (w + j * 8) * 16 + lq;
                const short8 bf = *(const short8*)(wbase + brow * 128 + ((((ks << 2) + lg) ^ (brow & 7)) << 4));
#pragma unroll
                for (int mf = 0; mf < 2; ++mf)
                    acc[mf][j] = __builtin_amdgcn_mfma_f32_16x16x32_bf16(af[mf], bf, acc[mf][j], 0, 0, 0);
            }
        }
        __builtin_amdgcn_s_setprio(0);
        __syncthreads();
    }

    // epilogue: C row m = mf*16+lg*4+r, cols: j=0 -> Q[w*16+lq], j=1 -> K, j=2 -> V d
    // LDS: Q [32][256B] @0, K @8192, V [128 d][64B] @16384 (all granule-swizzled)
#pragma unroll
    for (int mf = 0; mf < 2; ++mf)
#pragma unroll
        for (int r = 0; r < 4; ++r) {
            const int mrow = mf * 16 + lg * 4 + r;
            const int n = w * 16 + lq;
            *(u16*)(smem + mrow * 256 + (((n >> 3) ^ (mrow & 7)) << 4) + ((n & 7) << 1))
                = f2bf(acc[mf][0][r] * QS2);
            *(u16*)(smem + 8192 + mrow * 256 + (((n >> 3) ^ (mrow & 7)) << 4) + ((n & 7) << 1))
                = f2bf(acc[mf][1][r]);
            const int d = n, s = mrow;
            *(u16*)(smem + 16384 + d * 64 + (((s >> 3) ^ (d & 3)) << 4) + ((s & 7) << 1))
                = f2bf(acc[mf][2][r]);
        }
    __syncthreads();
    {
        const int b = m0 >> 11, s0b = m0 & 2047;
        const int mm2 = tid >> 4, gp = tid & 15;
        const int n0 = (gp ^ (mm2 & 7)) * 8;
        const short8 vq = *(const short8*)(smem + mm2 * 256 + (gp << 4));
        *(short8*)(Qb + (size_t)(m0 + mm2) * 128 + n0) = vq;
        const short8 vk = *(const short8*)(smem + 8192 + mm2 * 256 + (gp << 4));
        *(short8*)(Kb + (size_t)(m0 + mm2) * 128 + n0) = vk;
        const int d = tid >> 2, cg = tid & 3;
        const int sg = cg ^ (d & 3);
        const short8 vv = *(const short8*)(smem + 16384 + d * 64 + (cg << 4));
        *(short8*)(Vtb + (size_t)b * DDIM * SEQ + (size_t)d * SEQ + s0b + sg * 8) = vv;
    }
}

// ---------------- kernel 3: fused flash attention ----------------------------------------
// 256 blocks x 512 thr (8 waves = qi{0,1} x ki{0..3}). Block = 32 q-rows; wave = 16 q x
// 512 kv quarter, KVB=32, 16 iters. qi=0 stages K, qi=1 stages V. Double-buffered LDS.
// Mask packed in-kernel to a [32][66] u32 LDS bitmap. Softmax in exp2 domain.
__global__ __launch_bounds__(512, 1) void flash_kernel(
    const int* __restrict__ mask,
    const u16* __restrict__ Qb, const u16* __restrict__ Kb, const u16* __restrict__ Vtb,
    float* __restrict__ out)
{
    __shared__ __align__(16) uint8_t smem[139264];  // KV [4 ki][2 buf][K 8KB|V 8KB] @0, P [8][1KB] @131072
    __shared__ u32 mlds[2112];                       // [32 q][66] packed mask words (pad 66)
    __shared__ float ml_m[2][4][16], ml_l[2][4][16], recipL[32];

    const int tid = threadIdx.x;
    const int w = tid >> 6, lane = tid & 63;
    const int qi = w >> 2, ki = w & 3;
    const int lq = lane & 15, lg = lane >> 4;

    const int bid = blockIdx.x;
    const int qt = (bid & 7) * 32 + (bid >> 3);     // XCD-chunked: 32 contiguous q-tiles/XCD
    const int b = qt >> 6;
    const int q0 = (qt & 63) << 5;
    const size_t qrow0 = (size_t)b * SEQ + q0;

    const u16* Qp = Qb + (qrow0 + qi * 16) * 128;
    const u16* Kp = Kb + (size_t)b * SEQ * 128;
    const u16* Vp = Vtb + (size_t)b * DDIM * SEQ;

    uint8_t* kvb0 = smem + ki * 32768;              // [2 buf][16KB]
    uint8_t* pbase = smem + 131072 + w * 1024;      // P: [16 q][32 kv] bf16

    // staging: qi=0 -> K tile [32 kv][128 d]; qi=1 -> V tile [128 d][32 kv]
    auto stage = [&](uint8_t* kvb, int kv0) {
        if (qi == 0) {
#pragma unroll
            for (int i = 0; i < 8; ++i) {
                const int G = i * 64 + lane;
                const int row = G >> 4, c = G & 15;
                gld16(Kp + (size_t)(kv0 + row) * 128 + ((c ^ (row & 7)) << 3),
                      kvb + i * 1024);
            }
        } else {
#pragma unroll
            for (int i = 0; i < 8; ++i) {
                const int G = i * 64 + lane;
                const int dd = G >> 2, c = G & 3;
                gld16(Vp + (size_t)dd * SEQ + kv0 + ((c ^ ((dd ^ (dd >> 2)) & 3)) << 3),
                      kvb + 8192 + i * 1024);
            }
        }
    };

    // prologue: stage t=0 (async), pack mask while loads fly, load Q frags
    stage(kvb0, ki * 512);
    short8 qf[4];
#pragma unroll
    for (int ks = 0; ks < 4; ++ks)
        qf[ks] = *(const short8*)(Qp + (size_t)lq * 128 + ks * 32 + lg * 8);
    {
        const int r = tid >> 4, c0 = (tid & 15) * 4;     // 4 words per thread
        const int* srcm = mask + (qrow0 + r) * (size_t)SEQ + (size_t)c0 * 32;
#pragma unroll
        for (int j = 0; j < 4; ++j) {
            u32 bits = 0;
#pragma unroll
            for (int it = 0; it < 8; ++it) {
                const int4v v = *(const int4v*)(srcm + j * 32 + it * 4);
                bits |= (v[0] != 0 ? 1u : 0u) << (it * 4 + 0);
                bits |= (v[1] != 0 ? 1u : 0u) << (it * 4 + 1);
                bits |= (v[2] != 0 ? 1u : 0u) << (it * 4 + 2);
                bits |= (v[3] != 0 ? 1u : 0u) << (it * 4 + 3);
            }
            mlds[r * 66 + c0 + j] = bits;
        }
    }
    __syncthreads();                                 // drains gld16 (vmcnt) + mask writes

    f32x4 acc[8] = {};                  // O^T: acc[df][r] = O[q=lq][d=df*16+lg*4+r]
    float m = -1e30f, l = 0.0f;
    const int mbidx = (qi * 16 + lq) * 66 + ki * 16;

#pragma unroll 1
    for (int t = 0; t < 16; ++t) {
        uint8_t* kvb = kvb0 + (t & 1) * 16384;
        if (t < 15) stage(kvb0 + ((t + 1) & 1) * 16384, ki * 512 + (t + 1) * 32);
        const u32 mw = mlds[mbidx + t];
        __builtin_amdgcn_sched_barrier(0);

        // S^T = K Q : C row = kv (nf*16+lg*4+r), col = q (lq); logits in log2 domain
        f32x4 sacc[2] = {};
        __builtin_amdgcn_s_setprio(1);
#pragma unroll
        for (int ks = 0; ks < 4; ++ks)
#pragma unroll
            for (int nf = 0; nf < 2; ++nf) {
                const int krow = nf * 16 + lq;
                const short8 kf = *(const short8*)(kvb + krow * 256 + ((((ks << 2) + lg) ^ (krow & 7)) << 4));
                sacc[nf] = __builtin_amdgcn_mfma_f32_16x16x32_bf16(kf, qf[ks], sacc[nf], 0, 0, 0);
            }
        __builtin_amdgcn_s_setprio(0);

        // per-lane online softmax (exp2 domain) for q=lq over 32 kv
        float sv[2][4];
#pragma unroll
        for (int nf = 0; nf < 2; ++nf)
#pragma unroll
            for (int r = 0; r < 4; ++r)
                sv[nf][r] = sacc[nf][r] + (((mw >> (nf * 16 + lg * 4 + r)) & 1u) ? -1e15f : 0.0f);
        float tm = sv[0][0];
#pragma unroll
        for (int nf = 0; nf < 2; ++nf)
#pragma unroll
            for (int r = 0; r < 4; ++r) tm = fmaxf(tm, sv[nf][r]);
        tm = fmaxf(tm, __shfl_xor(tm, 16));
        tm = fmaxf(tm, __shfl_xor(tm, 32));
        if (!__all(tm <= m + 13.0f)) {              // defer-max (log2 domain, P <= 2^13)
            const float mnew = fmaxf(m, tm);
            const float sf = ex2(m - mnew);
            m = mnew;
            l *= sf;
#pragma unroll
            for (int df = 0; df < 8; ++df) acc[df] *= sf;
        }
        float p[2][4];
        float rs = 0.0f;
#pragma unroll
        for (int nf = 0; nf < 2; ++nf)
#pragma unroll
            for (int r = 0; r < 4; ++r) { p[nf][r] = ex2(sv[nf][r] - m); rs += p[nf][r]; }
        rs += __shfl_xor(rs, 16);
        rs += __shfl_xor(rs, 32);
        l += rs;

        // P -> per-wave LDS [q=lq][32 kv] via v_cvt_pk_bf16_f32 (4 x ds_write_b32)
#pragma unroll
        for (int nf = 0; nf < 2; ++nf)
#pragma unroll
            for (int h = 0; h < 2; ++h) {
                u32 pk;
                asm("v_cvt_pk_bf16_f32 %0, %1, %2" : "=v"(pk) : "v"(p[nf][2 * h]), "v"(p[nf][2 * h + 1]));
                const int kv = nf * 16 + lg * 4 + 2 * h;
                *(u32*)(pbase + lq * 64 + (((kv >> 3) ^ (lq & 3)) << 4) + ((kv << 1) & 15)) = pk;
            }
        const short8 pf = *(const short8*)(pbase + lq * 64 + ((lg ^ (lq & 3)) << 4));

        // O^T += V^T P
        __builtin_amdgcn_s_setprio(1);
#pragma unroll
        for (int df = 0; df < 8; ++df) {
            const int dd = df * 16 + lq;
            const short8 vf = *(const short8*)(kvb + 8192 + dd * 64 + ((lg ^ ((dd ^ (dd >> 2)) & 3)) << 4));
            acc[df] = __builtin_amdgcn_mfma_f32_16x16x32_bf16(vf, pf, acc[df], 0, 0, 0);
        }
        __builtin_amdgcn_s_setprio(0);

        asm volatile("s_waitcnt vmcnt(0)" ::: "memory");   // own stage loads (issued 1 iter ago)
        __builtin_amdgcn_s_barrier();                       // partner's too -> next buf ready
    }

    // ---- combine 4 kv-quarters per qi (log2-domain m/l) ----
    if (lg == 0) { ml_m[qi][ki][lq] = m; ml_l[qi][ki][lq] = l; }
    __syncthreads();
    {
        const float m0v = ml_m[qi][0][lq], m1v = ml_m[qi][1][lq];
        const float m2v = ml_m[qi][2][lq], m3v = ml_m[qi][3][lq];
        const float mm = fmaxf(fmaxf(m0v, m1v), fmaxf(m2v, m3v));
        const float Lg = ml_l[qi][0][lq] * ex2(m0v - mm) + ml_l[qi][1][lq] * ex2(m1v - mm)
                       + ml_l[qi][2][lq] * ex2(m2v - mm) + ml_l[qi][3][lq] * ex2(m3v - mm);
        if (ki == 0 && lg == 0) recipL[qi * 16 + lq] = 1.0f / Lg;
        const float s = ex2(m - mm);
        float* Ol = (float*)smem;                       // [2 qi][4 ki][16 q][132] f32
        float* dstq = Ol + ((size_t)(qi * 4 + ki) * 16 + lq) * 132;
#pragma unroll
        for (int df = 0; df < 8; ++df) {
            const f32x4 vsc = acc[df] * s;
            *(f32x4*)(dstq + df * 16 + lg * 4) = vsc;
        }
    }
    __syncthreads();
    {
        const float* Ol = (const float*)smem;
        const int row = tid >> 4, c0 = (tid & 15) * 8;  // row 0..31
        const int rqi = row >> 4, rq = row & 15;
        const float rl = recipL[row];
        f32x4 s0 = {}, s1 = {};
#pragma unroll
        for (int kk = 0; kk < 4; ++kk) {
            const float* p2 = Ol + ((size_t)(rqi * 4 + kk) * 16 + rq) * 132 + c0;
            s0 += *(const f32x4*)p2;
            s1 += *(const f32x4*)(p2 + 4);
        }
        s0 *= rl; s1 *= rl;
        float* op = out + (qrow0 + row) * 128 + c0;
        *(f32x4*)op = s0;
        *(f32x4*)(op + 4) = s1;
    }
}

// ---------------- launcher ---------------------------------------------------------------
extern "C" void kernel_launch(void* const* d_in, const int* in_sizes, int n_in,
                              void* d_out, int out_size, void* d_ws, size_t ws_size,
                              hipStream_t stream) {
    (void)in_sizes; (void)n_in; (void)out_size; (void)ws_size;
    const float* inputs = (const float*)d_in[0];
    const int*   mask   = (const int*)d_in[1];
    const float* Wq     = (const float*)d_in[2];
    const float* Wk     = (const float*)d_in[3];
    const float* Wv     = (const float*)d_in[4];
    float* out = (float*)d_out;

    uint8_t* ws = (uint8_t*)d_ws;
    u16* Wtb = (u16*)ws;                        //   786,432 B [384 n][1024 k] bf16 (Q|K|V)
    u16* Qb  = (u16*)(ws + 786432);             // 2,097,152 B [8192][128] bf16 (pre-scaled)
    u16* Kb  = (u16*)(ws + 2883584);            // 2,097,152 B
    u16* Vtb = (u16*)(ws + 4980736);            // 2,097,152 B [4][128][2048] bf16
    // total ws use: 7,077,888 B

    hipLaunchKernelGGL(prep_kernel, dim3(96), dim3(256), 0, stream, Wq, Wk, Wv, Wtb);
    hipLaunchKernelGGL(proj_kernel, dim3(256), dim3(512), 0, stream, inputs, Wtb, Qb, Kb, Vtb);
    hipLaunchKernelGGL(flash_kernel, dim3(256), dim3(512), 0, stream, mask, Qb, Kb, Vtb, out);
}

// Round 6
// 171.279 us; speedup vs baseline: 1.0208x; 1.0208x over previous
//
#include <hip/hip_runtime.h>
#include <stdint.h>

// AttentionHead: out = softmax(QK^T/sqrt(dk) - 1e15*mask) @ V, Q/K/V = inputs @ W{q,k,v}
// B=4 S=2048 E=1024 D=128. bf16 MFMA; split-KV flash (2 halves + reduce), exp2 domain,
// bit-packed mask (dedicated streaming kernel), fused A-read-once QKV projection.

#define SEQ   2048
#define EDIM  1024
#define DDIM  128
#define QS2   0.1275174329f   // (1/sqrt(128)) * log2(e)

typedef unsigned short u16;
typedef unsigned int   u32;
using short8 = __attribute__((ext_vector_type(8))) short;   // 8 x bf16 (4 VGPR) MFMA frag
using f32x4  = __attribute__((ext_vector_type(4))) float;
using int4v  = __attribute__((ext_vector_type(4))) int;
using u32x2  = __attribute__((ext_vector_type(2))) unsigned int;

__device__ __forceinline__ u16 f2bf(float x) {              // f32 -> bf16 RNE
    uint32_t u = __float_as_uint(x);
    return (u16)((u + 0x7fffu + ((u >> 16) & 1u)) >> 16);
}
__device__ __forceinline__ float ex2(float x) {             // 2^x
    float r; asm("v_exp_f32 %0, %1" : "=v"(r) : "v"(x)); return r;
}

// async global->LDS 16B per lane; LDS dst = wave-uniform base + lane*16 (linear).
__device__ __forceinline__ void gld16(const void* gsrc, void* lds_dst) {
    __builtin_amdgcn_global_load_lds(
        (const __attribute__((address_space(1))) uint32_t*)(uintptr_t)gsrc,
        (__attribute__((address_space(3))) uint32_t*)(uint32_t)(uintptr_t)lds_dst,
        16, 0, 0);
}

// ---------------- kernel 1: prep = mask bit-pack (coalesced) + W transpose ---------------
// blocks [0,2048): pack 8192 mask ints -> 256 u32 words. blocks [2048,2144): W->Wt bf16.
__global__ __launch_bounds__(256) void prep_kernel(
    const int* __restrict__ mask,
    const float* __restrict__ Wq, const float* __restrict__ Wk, const float* __restrict__ Wv,
    u32* __restrict__ Mbits, u16* __restrict__ Wt)
{
    __shared__ u32 nib32[2048];
    __shared__ u16 tl[64][65];
    const int bx = blockIdx.x;
    const int tid = threadIdx.x;
    if (bx < 2048) {
        const int* src = mask + (size_t)bx * 8192;
#pragma unroll
        for (int it = 0; it < 8; ++it) {
            const int idx = it * 256 + tid;
            const int4v v = *(const int4v*)(src + idx * 4);   // 16B/lane contiguous
            const u32 nb = (v[0] != 0 ? 1u : 0u) | (v[1] != 0 ? 2u : 0u)
                         | (v[2] != 0 ? 4u : 0u) | (v[3] != 0 ? 8u : 0u);
            nib32[(idx & 7) * 256 + ((idx >> 3) ^ ((idx & 7) << 2))] = nb;
        }
        __syncthreads();
        u32 word = 0;
#pragma unroll
        for (int j = 0; j < 8; ++j)
            word |= (nib32[j * 256 + (tid ^ (j << 2))] & 0xFu) << (4 * j);
        Mbits[bx * 256 + tid] = word;
    } else {
        const int t = bx - 2048;                              // 96 = 3 mats * 32 tiles
        const int wsel = t >> 5;
        const int tile = t & 31;
        const int k0 = (tile >> 1) * 64;
        const int n0 = (tile & 1) * 64;
        const float* W = (wsel == 0) ? Wq : ((wsel == 1) ? Wk : Wv);
#pragma unroll
        for (int it = 0; it < 16; ++it) {
            const int idx = it * 256 + tid;
            const int r = idx >> 6, c = idx & 63;
            tl[c][r] = f2bf(W[(size_t)(k0 + r) * DDIM + n0 + c]);
        }
        __syncthreads();
        u16* Wtp = Wt + (size_t)wsel * DDIM * EDIM;
#pragma unroll
        for (int it = 0; it < 16; ++it) {
            const int idx = it * 256 + tid;
            const int r = idx >> 6, c = idx & 63;
            Wtp[(size_t)(n0 + r) * EDIM + k0 + c] = tl[r][c];
        }
    }
}

// ---------------- kernel 2: fused QKV projection (unchanged from round 5) ----------------
__global__ __launch_bounds__(512, 1) void proj_kernel(
    const float* __restrict__ Ain, const u16* __restrict__ Wtb,
    u16* __restrict__ Qb, u16* __restrict__ Kb, u16* __restrict__ Vtb)
{
    __shared__ __align__(16) uint8_t smem[106496];  // A[2] 8KB @0, Wt[2] 96KB @8192
    const int tid = threadIdx.x;
    const int w = tid >> 6, lane = tid & 63;
    const int lq = lane & 15, lg = lane >> 4;

    const int bid = blockIdx.x;                      // 256 = 8 xcd * 32
    const int wg = (bid & 7) * 32 + (bid >> 3);
    const int m0 = wg * 32;

    f32x4 acc[2][3] = {};

    auto stageP = [&](int buf, int kt) {
        const int k0 = kt * 64;
        uint8_t* wtb = smem + 8192 + buf * 49152;
#pragma unroll
        for (int i = 0; i < 6; ++i) {
            const int G = i * 512 + tid;
            const int n = G >> 3, c = G & 7;
            gld16(Wtb + (size_t)n * EDIM + k0 + ((c ^ (n & 7)) << 3),
                  wtb + i * 8192 + w * 1024);
        }
        const int row = tid >> 4, c4 = tid & 15;
        const int c2 = c4 >> 1, h = c4 & 1;
        const float* s2 = Ain + (size_t)(m0 + row) * EDIM + k0 + c2 * 8 + h * 4;
        const f32x4 a0 = *(const f32x4*)s2;
        u32x2 pk;
        pk[0] = (u32)f2bf(a0[0]) | ((u32)f2bf(a0[1]) << 16);
        pk[1] = (u32)f2bf(a0[2]) | ((u32)f2bf(a0[3]) << 16);
        *(u32x2*)(smem + buf * 4096 + row * 128 + ((c2 ^ (row & 7)) << 4) + h * 8) = pk;
    };

    stageP(0, 0);
    __syncthreads();

#pragma unroll 1
    for (int kt = 0; kt < 16; ++kt) {
        const int cur = kt & 1;
        if (kt < 15) stageP(cur ^ 1, kt + 1);
        const uint8_t* abase = smem + cur * 4096;
        const uint8_t* wbase = smem + 8192 + cur * 49152;
        __builtin_amdgcn_s_setprio(1);
#pragma unroll
        for (int ks = 0; ks < 2; ++ks) {
            short8 af[2];
#pragma unroll
            for (int mf = 0; mf < 2; ++mf) {
                const int arow = mf * 16 + lq;
                af[mf] = *(const short8*)(abase + arow * 128 + ((((ks << 2) + lg) ^ (arow & 7)) << 4));
            }
#pragma unroll
            for (int j = 0; j < 3; ++j) {
                const int brow = (w + j * 8) * 16 + lq;
                const short8 bf = *(const short8*)(wbase + brow * 128 + ((((ks << 2) + lg) ^ (brow & 7)) << 4));
#pragma unroll
                for (int mf = 0; mf < 2; ++mf)
                    acc[mf][j] = __builtin_amdgcn_mfma_f32_16x16x32_bf16(af[mf], bf, acc[mf][j], 0, 0, 0);
            }
        }
        __builtin_amdgcn_s_setprio(0);
        __syncthreads();
    }

    // epilogue: C row m = mf*16+lg*4+r, cols: j=0 -> Q, j=1 -> K, j=2 -> V(d)
#pragma unroll
    for (int mf = 0; mf < 2; ++mf)
#pragma unroll
        for (int r = 0; r < 4; ++r) {
            const int mrow = mf * 16 + lg * 4 + r;
            const int n = w * 16 + lq;
            *(u16*)(smem + mrow * 256 + (((n >> 3) ^ (mrow & 7)) << 4) + ((n & 7) << 1))
                = f2bf(acc[mf][0][r] * QS2);
            *(u16*)(smem + 8192 + mrow * 256 + (((n >> 3) ^ (mrow & 7)) << 4) + ((n & 7) << 1))
                = f2bf(acc[mf][1][r]);
            const int d = n, s = mrow;
            *(u16*)(smem + 16384 + d * 64 + (((s >> 3) ^ (d & 3)) << 4) + ((s & 7) << 1))
                = f2bf(acc[mf][2][r]);
        }
    __syncthreads();
    {
        const int b = m0 >> 11, s0b = m0 & 2047;
        const int mm2 = tid >> 4, gp = tid & 15;
        const int n0 = (gp ^ (mm2 & 7)) * 8;
        const short8 vq = *(const short8*)(smem + mm2 * 256 + (gp << 4));
        *(short8*)(Qb + (size_t)(m0 + mm2) * 128 + n0) = vq;
        const short8 vk = *(const short8*)(smem + 8192 + mm2 * 256 + (gp << 4));
        *(short8*)(Kb + (size_t)(m0 + mm2) * 128 + n0) = vk;
        const int d = tid >> 2, cg = tid & 3;
        const int sg = cg ^ (d & 3);
        const short8 vv = *(const short8*)(smem + 16384 + d * 64 + (cg << 4));
        *(short8*)(Vtb + (size_t)b * DDIM * SEQ + (size_t)d * SEQ + s0b + sg * 8) = vv;
    }
}

// ---------------- kernel 3: split-KV flash attention -------------------------------------
// 512 blocks x 512 thr: (qt 0..255) x (kv-half h 0..1). 8 waves = qi{0,1} x ki{0..3};
// wave = 16 q x 256 kv, KVB=32, 8 iters. Single-buffered shared KV tiles (2 blocks/CU).
// qi=0 stages K after QK-barrier (hides under softmax+PV); qi=1 stages V after PV-barrier.
// Writes unnormalized partials + (m,l) per row; reduce_kernel combines halves.
__global__ __launch_bounds__(512, 4) void flash_kernel(
    const u32* __restrict__ Mb,
    const u16* __restrict__ Qb, const u16* __restrict__ Kb, const u16* __restrict__ Vtb,
    float* __restrict__ Opart, float* __restrict__ Mpart, float* __restrict__ Lpart)
{
    __shared__ __align__(16) uint8_t smem[73728];   // KV 4ki x (K 8KB|V 8KB) @0, P 8x1KB @65536
    __shared__ float ml_m[2][4][16], ml_l[2][4][16];

    const int tid = threadIdx.x;
    const int w = tid >> 6, lane = tid & 63;
    const int qi = w >> 2, ki = w & 3;
    const int lq = lane & 15, lg = lane >> 4;

    const int bid = blockIdx.x;                     // 512 = 8 xcd * 64
    const int u = bid >> 3, xcd = bid & 7;
    const int qt = xcd * 32 + (u & 31);             // 32 contiguous q-tiles per XCD
    const int h = u >> 5;                           // kv half
    const int b = qt >> 6;
    const int q0 = (qt & 63) << 5;
    const size_t qrow0 = (size_t)b * SEQ + q0;

    const u16* Qp = Qb + (qrow0 + qi * 16) * 128;
    const u16* Kp = Kb + (size_t)b * SEQ * 128;
    const u16* Vp = Vtb + (size_t)b * DDIM * SEQ;
    const u32* mrp = Mb + (qrow0 + qi * 16 + lq) * 64 + h * 32 + ki * 8;

    const int kv00 = h * 1024 + ki * 256;
    uint8_t* kvb = smem + ki * 16384;               // K @0, V @8192 (single buffer)
    uint8_t* pbase = smem + 65536 + w * 1024;       // P: [16 q][32 kv] bf16

    auto stageK = [&](int kv0) {
#pragma unroll
        for (int i = 0; i < 8; ++i) {
            const int G = i * 64 + lane;
            const int row = G >> 4, c = G & 15;
            gld16(Kp + (size_t)(kv0 + row) * 128 + ((c ^ (row & 7)) << 3),
                  kvb + i * 1024);
        }
    };
    auto stageV = [&](int kv0) {
#pragma unroll
        for (int i = 0; i < 8; ++i) {
            const int G = i * 64 + lane;
            const int dd = G >> 2, c = G & 3;
            gld16(Vp + (size_t)dd * SEQ + kv0 + ((c ^ ((dd ^ (dd >> 2)) & 3)) << 3),
                  kvb + 8192 + i * 1024);
        }
    };

    // prologue: stage t=0, load Q frags + first mask word
    if (qi == 0) stageK(kv00); else stageV(kv00);
    short8 qf[4];
#pragma unroll
    for (int ks = 0; ks < 4; ++ks)
        qf[ks] = *(const short8*)(Qp + (size_t)lq * 128 + ks * 32 + lg * 8);
    u32 mw = mrp[0];
    __syncthreads();

    f32x4 acc[8] = {};                  // O^T: acc[df][r] = O[q=lq][d=df*16+lg*4+r]
    float m = -1e30f, l = 0.0f;

#pragma unroll 1
    for (int t = 0; t < 8; ++t) {
        // S^T = K Q : C row = kv (nf*16+lg*4+r), col = q (lq); logits in log2 domain
        f32x4 sacc[2] = {};
        __builtin_amdgcn_s_setprio(1);
#pragma unroll
        for (int ks = 0; ks < 4; ++ks)
#pragma unroll
            for (int nf = 0; nf < 2; ++nf) {
                const int krow = nf * 16 + lq;
                const short8 kf = *(const short8*)(kvb + krow * 256 + ((((ks << 2) + lg) ^ (krow & 7)) << 4));
                sacc[nf] = __builtin_amdgcn_mfma_f32_16x16x32_bf16(kf, qf[ks], sacc[nf], 0, 0, 0);
            }
        __builtin_amdgcn_s_setprio(0);
        __syncthreads();                              // (a) K readers done
        if (qi == 0 && t < 7) stageK(kv00 + (t + 1) * 32);   // lands by barrier (b)

        // per-lane online softmax (exp2 domain) for q=lq over 32 kv
        float sv[2][4];
#pragma unroll
        for (int nf = 0; nf < 2; ++nf)
#pragma unroll
            for (int r = 0; r < 4; ++r)
                sv[nf][r] = sacc[nf][r] + (((mw >> (nf * 16 + lg * 4 + r)) & 1u) ? -1e15f : 0.0f);
        float tm = sv[0][0];
#pragma unroll
        for (int nf = 0; nf < 2; ++nf)
#pragma unroll
            for (int r = 0; r < 4; ++r) tm = fmaxf(tm, sv[nf][r]);
        tm = fmaxf(tm, __shfl_xor(tm, 16));
        tm = fmaxf(tm, __shfl_xor(tm, 32));
        if (!__all(tm <= m + 13.0f)) {               // defer-max (log2 domain, P <= 2^13)
            const float mnew = fmaxf(m, tm);
            const float sf = ex2(m - mnew);
            m = mnew;
            l *= sf;
#pragma unroll
            for (int df = 0; df < 8; ++df) acc[df] *= sf;
        }
        float p[2][4];
        float rs = 0.0f;
#pragma unroll
        for (int nf = 0; nf < 2; ++nf)
#pragma unroll
            for (int r = 0; r < 4; ++r) { p[nf][r] = ex2(sv[nf][r] - m); rs += p[nf][r]; }
        rs += __shfl_xor(rs, 16);
        rs += __shfl_xor(rs, 32);
        l += rs;

        // P -> per-wave LDS [q=lq][32 kv] via v_cvt_pk_bf16_f32 (4 x ds_write_b32)
#pragma unroll
        for (int nf = 0; nf < 2; ++nf)
#pragma unroll
            for (int hh = 0; hh < 2; ++hh) {
                u32 pk;
                asm("v_cvt_pk_bf16_f32 %0, %1, %2" : "=v"(pk) : "v"(p[nf][2 * hh]), "v"(p[nf][2 * hh + 1]));
                const int kv = nf * 16 + lg * 4 + 2 * hh;
                *(u32*)(pbase + lq * 64 + (((kv >> 3) ^ (lq & 3)) << 4) + ((kv << 1) & 15)) = pk;
            }
        const short8 pf = *(const short8*)(pbase + lq * 64 + ((lg ^ (lq & 3)) << 4));

        // O^T += V^T P
        __builtin_amdgcn_s_setprio(1);
#pragma unroll
        for (int df = 0; df < 8; ++df) {
            const int dd = df * 16 + lq;
            const short8 vf = *(const short8*)(kvb + 8192 + dd * 64 + ((lg ^ ((dd ^ (dd >> 2)) & 3)) << 4));
            acc[df] = __builtin_amdgcn_mfma_f32_16x16x32_bf16(vf, pf, acc[df], 0, 0, 0);
        }
        __builtin_amdgcn_s_setprio(0);
        __syncthreads();                              // (b) V readers done (+K stage drained)
        if (qi == 1 && t < 7) stageV(kv00 + (t + 1) * 32);
        const u32 mwn = (t < 7) ? mrp[t + 1] : 0u;
        __syncthreads();                              // (c) V stage + mask drained
        mw = mwn;
    }

    // ---- combine 4 kv-quarters per qi; write unnormalized partial + (m,l) ----
    if (lg == 0) { ml_m[qi][ki][lq] = m; ml_l[qi][ki][lq] = l; }
    __syncthreads();
    {
        const float m0v = ml_m[qi][0][lq], m1v = ml_m[qi][1][lq];
        const float m2v = ml_m[qi][2][lq], m3v = ml_m[qi][3][lq];
        const float mm = fmaxf(fmaxf(m0v, m1v), fmaxf(m2v, m3v));
        const float Lg = ml_l[qi][0][lq] * ex2(m0v - mm) + ml_l[qi][1][lq] * ex2(m1v - mm)
                       + ml_l[qi][2][lq] * ex2(m2v - mm) + ml_l[qi][3][lq] * ex2(m3v - mm);
        if (ki == 0 && lg == 0) {
            Mpart[h * 8192 + qrow0 + qi * 16 + lq] = mm;
            Lpart[h * 8192 + qrow0 + qi * 16 + lq] = Lg;
        }
        const float s = ex2(m - mm);
        float* Ol = (float*)smem;                    // [2 qi][4 ki][16 q][132] f32
        float* dstq = Ol + ((size_t)(qi * 4 + ki) * 16 + lq) * 132;
#pragma unroll
        for (int df = 0; df < 8; ++df) {
            const f32x4 vsc = acc[df] * s;
            *(f32x4*)(dstq + df * 16 + lg * 4) = vsc;
        }
    }
    __syncthreads();
    {
        const float* Ol = (const float*)smem;
        const int row = tid >> 4, c0 = (tid & 15) * 8;  // row 0..31
        const int rqi = row >> 4, rq = row & 15;
        f32x4 s0 = {}, s1 = {};
#pragma unroll
        for (int kk = 0; kk < 4; ++kk) {
            const float* p2 = Ol + ((size_t)(rqi * 4 + kk) * 16 + rq) * 132 + c0;
            s0 += *(const f32x4*)p2;
            s1 += *(const f32x4*)(p2 + 4);
        }
        float* op = Opart + ((size_t)(h * 8192) + qrow0 + row) * 128 + c0;
        *(f32x4*)op = s0;
        *(f32x4*)(op + 4) = s1;
    }
}

// ---------------- kernel 4: combine the two kv-half partials -----------------------------
__global__ __launch_bounds__(256) void reduce_kernel(
    const float* __restrict__ Op, const float* __restrict__ Mp,
    const float* __restrict__ Lp, float* __restrict__ out)
{
    const int row = blockIdx.x * 16 + (threadIdx.x >> 4);
    const int c0 = (threadIdx.x & 15) * 8;
    const float m0 = Mp[row], m1 = Mp[8192 + row];
    const float l0 = Lp[row], l1 = Lp[8192 + row];
    const float M = fmaxf(m0, m1);
    const float e0 = ex2(m0 - M), e1 = ex2(m1 - M);
    const float rl = 1.0f / (l0 * e0 + l1 * e1);
    const float* p0 = Op + (size_t)row * 128 + c0;
    const float* p1 = Op + (size_t)(8192 + row) * 128 + c0;
    f32x4 a0 = *(const f32x4*)p0 * e0 + *(const f32x4*)p1 * e1;
    f32x4 a1 = *(const f32x4*)(p0 + 4) * e0 + *(const f32x4*)(p1 + 4) * e1;
    *(f32x4*)(out + (size_t)row * 128 + c0) = a0 * rl;
    *(f32x4*)(out + (size_t)row * 128 + c0 + 4) = a1 * rl;
}

// ---------------- launcher ---------------------------------------------------------------
extern "C" void kernel_launch(void* const* d_in, const int* in_sizes, int n_in,
                              void* d_out, int out_size, void* d_ws, size_t ws_size,
                              hipStream_t stream) {
    (void)in_sizes; (void)n_in; (void)out_size; (void)ws_size;
    const float* inputs = (const float*)d_in[0];
    const int*   mask   = (const int*)d_in[1];
    const float* Wq     = (const float*)d_in[2];
    const float* Wk     = (const float*)d_in[3];
    const float* Wv     = (const float*)d_in[4];
    float* out = (float*)d_out;

    uint8_t* ws = (uint8_t*)d_ws;
    u16*   Wtb   = (u16*)ws;                     //   786,432 B [384 n][1024 k] bf16 (Q|K|V)
    u16*   Qb    = (u16*)(ws + 786432);          // 2,097,152 B [8192][128] bf16 (pre-scaled)
    u16*   Kb    = (u16*)(ws + 2883584);         // 2,097,152 B
    u16*   Vtb   = (u16*)(ws + 4980736);         // 2,097,152 B [4][128][2048] bf16
    u32*   Mbits = (u32*)(ws + 7077888);         // 2,097,152 B [4*2048][64] u32
    float* Opart = (float*)(ws + 9175040);       // 8,388,608 B [2][8192][128] f32
    float* Mpart = (float*)(ws + 17563648);      //    65,536 B [2][8192] f32
    float* Lpart = (float*)(ws + 17629184);      //    65,536 B [2][8192] f32
    // total ws use: 17,694,720 B

    hipLaunchKernelGGL(prep_kernel, dim3(2144), dim3(256), 0, stream, mask, Wq, Wk, Wv, Mbits, Wtb);
    hipLaunchKernelGGL(proj_kernel, dim3(256), dim3(512), 0, stream, inputs, Wtb, Qb, Kb, Vtb);
    hipLaunchKernelGGL(flash_kernel, dim3(512), dim3(512), 0, stream, Mbits, Qb, Kb, Vtb, Opart, Mpart, Lpart);
    hipLaunchKernelGGL(reduce_kernel, dim3(512), dim3(256), 0, stream, Opart, Mpart, Lpart, out);
}